// Round 6
// baseline (254.837 us; speedup 1.0000x reference)
//
#include <hip/hip_runtime.h>

// DGCNN fused: 2x GCNConv + sort-pool(k=70) + folded MLP + sigmoid.
// K0: weff = lw1@lw2 (+beff).  K1: one block/graph, 1024 thr (16 waves),
// 2 blocks/CU -> 32 waves/CU. VGPR must stay <=64 (launch_bounds(1024,8)).

#define NG      512
#define NPG     90
#define EPG     1440
#define IN_DIM  90
#define HD      64
#define KP      70
#define E_TOT   (NG*EPG)
#define NT      1024

__global__ __launch_bounds__(256) void weff_fold(
    const float* __restrict__ lw1, const float* __restrict__ lb1,
    const float* __restrict__ lw2, const float* __restrict__ lb2,
    float* __restrict__ ws)
{
    int i = blockIdx.x*256 + threadIdx.x;
    if (i < KP*HD) {
        const float4* row = (const float4*)(lw1 + (size_t)i*HD);
        const float4* w   = (const float4*)lw2;
        float s = 0.f;
        #pragma unroll
        for (int j4 = 0; j4 < HD/4; ++j4) {
            float4 r = row[j4], v = w[j4];
            s += r.x*v.x + r.y*v.y + r.z*v.z + r.w*v.w;
        }
        ws[i] = s;
    } else if (i == KP*HD) {
        float s = lb2[0];
        for (int j = 0; j < HD; ++j) s += lb1[j]*lw2[j];
        ws[KP*HD] = s;
    }
}

__global__ __launch_bounds__(NT, 8) void dgcnn_fused(
    const float* __restrict__ x,     // [46080,90]
    const int*   __restrict__ ei,    // [2,E]
    const float* __restrict__ ew,    // [E]
    const float* __restrict__ W1,    // [90,64]
    const float* __restrict__ b1,    // [64]
    const float* __restrict__ W2,    // [64,64]
    const float* __restrict__ b2,    // [64]
    const float* __restrict__ weff,  // [4481] from K0
    float* __restrict__ out,         // [512]
    float* __restrict__ xtrain)      // [46080,64]
{
    __shared__ float sB[NPG*HD];           // xw / hw2
    __shared__ float sC[NPG*HD];           // W1 stage -> h1(relu) -> h2
    __shared__ float sW2[HD*HD];
    __shared__ float s_dinv[NPG];          // deg -> dinv (in place)
    __shared__ int   s_indeg[NPG];
    __shared__ int   s_cursor[NPG];
    __shared__ int   s_rowstart[NPG+1];
    __shared__ unsigned s_epack[EPG];      // norm (hi 25 bits) | src (low 7)
    __shared__ int   s_ranknode[KP];
    __shared__ float s_red[16];
    __shared__ int   s_itmp;

    const int g = blockIdx.x;
    const int t = threadIdx.x;
    const int j = t & 63;
    const int grp = t >> 6;                // wave id 0..15
    const int ebase = g*EPG;
    const int nbase = g*NPG;

    // ---- A: init ----
    if (t < NPG) { s_dinv[t] = 1.0f; s_indeg[t] = 0; }
    __syncthreads();

    // ---- B: degree + indegree (atomics); stage W1 -> sC ----
    for (int e = t; e < EPG; e += NT) {
        int d = ei[E_TOT + ebase + e] - nbase;
        float w = ew[ebase + e];
        atomicAdd(&s_dinv[d], w);
        atomicAdd(&s_indeg[d], 1);
    }
    for (int i4 = t; i4 < IN_DIM*HD/4; i4 += NT)
        ((float4*)sC)[i4] = ((const float4*)W1)[i4];
    __syncthreads();

    // ---- C: dinv in place + shfl-scan of indegree + cursor init ----
    if (t < NPG) s_dinv[t] = rsqrtf(fmaxf(s_dinv[t], 1e-12f));
    {
        int vi = (t < NPG) ? s_indeg[t] : 0;
        int inc = vi;
        #pragma unroll
        for (int d = 1; d < 64; d <<= 1) {
            int up = __shfl_up(inc, d, 64);
            if ((t & 63) >= d) inc += up;
        }
        if (t == 63) s_itmp = inc;           // total of indices 0..63
        __syncthreads();
        if (t <= NPG) {
            int base = (grp == 1) ? s_itmp : 0;
            int excl = inc - vi + base;
            s_rowstart[t] = excl;
            if (t < NPG) s_cursor[t] = excl;
        }
    }
    __syncthreads();

    // ---- D: CSR fill, packed u32 {norm[31:7], src[6:0]} (ei/ew L2-hot) ----
    for (int e = t; e < EPG; e += NT) {
        int s = ei[ebase + e] - nbase;
        int d = ei[E_TOT + ebase + e] - nbase;
        float nrm = s_dinv[s] * ew[ebase + e] * s_dinv[d];
        int pos = atomicAdd(&s_cursor[d], 1);
        s_epack[pos] = (__float_as_uint(nrm) & ~127u) | (unsigned)s;
    }
    __syncthreads();

    // ---- E: layer1 matmul sB = x_g @ W1, 4 rows/wave/it, 2 its ----
    const float* xg = x + (size_t)nbase * IN_DIM;
    for (int it = 0; it < 2; ++it) {
        int r0 = it*64 + grp*4;
        if (r0 < NPG) {
            int rr0 = min(r0+0, NPG-1), rr1 = min(r0+1, NPG-1);
            int rr2 = min(r0+2, NPG-1), rr3 = min(r0+3, NPG-1);
            const float2* xp0 = (const float2*)(xg + rr0*IN_DIM);
            const float2* xp1 = (const float2*)(xg + rr1*IN_DIM);
            const float2* xp2 = (const float2*)(xg + rr2*IN_DIM);
            const float2* xp3 = (const float2*)(xg + rr3*IN_DIM);
            float a0 = 0.f, a1 = 0.f, a2 = 0.f, a3 = 0.f;
            #pragma unroll 9
            for (int kh = 0; kh < IN_DIM/2; ++kh) {
                float w0 = sC[(2*kh)*HD + j];
                float w1 = sC[(2*kh+1)*HD + j];
                float2 v0 = xp0[kh], v1 = xp1[kh], v2 = xp2[kh], v3 = xp3[kh];
                a0 += v0.x*w0 + v0.y*w1;
                a1 += v1.x*w0 + v1.y*w1;
                a2 += v2.x*w0 + v2.y*w1;
                a3 += v3.x*w0 + v3.y*w1;
            }
            if (r0+0 < NPG) sB[(r0+0)*HD + j] = a0;
            if (r0+1 < NPG) sB[(r0+1)*HD + j] = a1;
            if (r0+2 < NPG) sB[(r0+2)*HD + j] = a2;
            if (r0+3 < NPG) sB[(r0+3)*HD + j] = a3;
        }
    }
    __syncthreads();

    // ---- F: scatter1 + bias + xtrain store + relu -> sC; stage W2 ----
    float* xt = xtrain + (size_t)nbase * HD;
    for (int o = t; o < NPG*HD; o += NT) {
        int d = o >> 6, c = o & 63;
        float dv = s_dinv[d];
        float a = dv*dv*sB[o];
        int p0 = s_rowstart[d], p1 = s_rowstart[d+1];
        for (int p = p0; p < p1; ++p) {
            unsigned u = s_epack[p];
            a += __uint_as_float(u & ~127u) * sB[(int)(u & 127u)*HD + c];
        }
        a += b1[c];
        xt[o] = a;
        sC[o] = fmaxf(a, 0.f);
    }
    for (int i4 = t; i4 < HD*HD/4; i4 += NT)
        ((float4*)sW2)[i4] = ((const float4*)W2)[i4];
    __syncthreads();

    // ---- H: layer2 matmul sB = relu(h1) @ W2 (W2 in LDS) ----
    for (int it = 0; it < 2; ++it) {
        int r0 = it*64 + grp*4;
        if (r0 < NPG) {
            int rr0 = min(r0+0, NPG-1), rr1 = min(r0+1, NPG-1);
            int rr2 = min(r0+2, NPG-1), rr3 = min(r0+3, NPG-1);
            float a0 = 0.f, a1 = 0.f, a2 = 0.f, a3 = 0.f;
            #pragma unroll 4
            for (int k4 = 0; k4 < HD/4; ++k4) {
                int k = k4*4;
                float4 h0 = *(const float4*)&sC[rr0*HD + k];
                float4 h1 = *(const float4*)&sC[rr1*HD + k];
                float4 h2 = *(const float4*)&sC[rr2*HD + k];
                float4 h3 = *(const float4*)&sC[rr3*HD + k];
                float w0 = sW2[(k+0)*HD + j];
                float w1 = sW2[(k+1)*HD + j];
                float w2 = sW2[(k+2)*HD + j];
                float w3 = sW2[(k+3)*HD + j];
                a0 += h0.x*w0 + h0.y*w1 + h0.z*w2 + h0.w*w3;
                a1 += h1.x*w0 + h1.y*w1 + h1.z*w2 + h1.w*w3;
                a2 += h2.x*w0 + h2.y*w1 + h2.z*w2 + h2.w*w3;
                a3 += h3.x*w0 + h3.y*w1 + h3.z*w2 + h3.w*w3;
            }
            if (r0+0 < NPG) sB[(r0+0)*HD + j] = a0;
            if (r0+1 < NPG) sB[(r0+1)*HD + j] = a1;
            if (r0+2 < NPG) sB[(r0+2)*HD + j] = a2;
            if (r0+3 < NPG) sB[(r0+3)*HD + j] = a3;
        }
    }
    __syncthreads();

    // ---- I: scatter2 -> sC ----
    for (int o = t; o < NPG*HD; o += NT) {
        int d = o >> 6, c = o & 63;
        float dv = s_dinv[d];
        float a = dv*dv*sB[o];
        int p0 = s_rowstart[d], p1 = s_rowstart[d+1];
        for (int p = p0; p < p1; ++p) {
            unsigned u = s_epack[p];
            a += __uint_as_float(u & ~127u) * sB[(int)(u & 127u)*HD + c];
        }
        sC[o] = a + b2[c];
    }
    __syncthreads();

    // ---- J: sort-pool rank, 8 threads/node (stable desc on ch 63) ----
    if (t < NPG*8) {
        int n = t >> 3, q = t & 7;
        float vi = sC[n*HD + (HD-1)];
        int cnt = 0;
        #pragma unroll 12
        for (int m = 0; m < 12; ++m) {
            int jj = q*12 + m;
            if (jj < NPG) {
                float vj = sC[jj*HD + (HD-1)];
                cnt += (vj > vi) || (vj == vi && jj < n);
            }
        }
        cnt += __shfl_down(cnt, 4, 8);
        cnt += __shfl_down(cnt, 2, 8);
        cnt += __shfl_down(cnt, 1, 8);
        if (q == 0 && cnt < KP) s_ranknode[cnt] = n;
    }
    __syncthreads();

    // ---- K: folded MLP = dot(pooled, weff) + beff -> sigmoid ----
    float part = 0.f;
    #pragma unroll
    for (int m = 0; m < 5; ++m) {
        int i = t + m*NT;
        if (i < KP*HD) {
            int k = i >> 6, c = i & 63;               // k uniform per wave
            part += weff[i] * sC[s_ranknode[k]*HD + c];
        }
    }
    #pragma unroll
    for (int off = 32; off > 0; off >>= 1) part += __shfl_down(part, off, 64);
    if (j == 0) s_red[grp] = part;
    __syncthreads();
    if (t == 0) {
        float zz = weff[KP*HD];
        #pragma unroll
        for (int m = 0; m < 16; ++m) zz += s_red[m];
        out[g] = 1.0f / (1.0f + expf(-zz));
    }
}

extern "C" void kernel_launch(void* const* d_in, const int* in_sizes, int n_in,
                              void* d_out, int out_size, void* d_ws, size_t ws_size,
                              hipStream_t stream) {
    const float* x   = (const float*)d_in[0];
    const int*   ei  = (const int*)  d_in[1];
    const float* ew  = (const float*)d_in[2];
    const float* W1  = (const float*)d_in[4];
    const float* b1  = (const float*)d_in[5];
    const float* W2  = (const float*)d_in[6];
    const float* b2  = (const float*)d_in[7];
    const float* lw1 = (const float*)d_in[8];
    const float* lb1 = (const float*)d_in[9];
    const float* lw2 = (const float*)d_in[10];
    const float* lb2 = (const float*)d_in[11];

    float* ws     = (float*)d_ws;         // weff[4480] + beff
    float* out    = (float*)d_out;        // [512]
    float* xtrain = out + NG;             // [46080*64]

    weff_fold<<<(KP*HD + 256)/256, 256, 0, stream>>>(lw1, lb1, lw2, lb2, ws);
    dgcnn_fused<<<NG, NT, 0, stream>>>(x, ei, ew, W1, b1, W2, b2,
                                       ws, out, xtrain);
}

// Round 7
// 177.472 us; speedup vs baseline: 1.4359x; 1.4359x over previous
//
#include <hip/hip_runtime.h>

// DGCNN pipeline, 5 kernels (R7): wide grids instead of one fused block/graph.
// K0: per-graph CSR/norm/dinv^2 -> ws (+weff fold in blocks 0..17)
// K1: xw = x @ W1        (2880 blocks, 16 rows each) -> xtrain region (transient)
// K2: h1 = Ahat xw + b1  (2048 blocks = graph x col-quarter), in-place -> xtrain
// K3: hw2 = relu(h1)@W2  (2880 blocks) -> ws
// K4: h2 = Ahat hw2 + b2 ; sort-pool ; folded MLP ; sigmoid (512 blocks x 512)

#define NG      512
#define NPG     90
#define EPG     1440
#define IN_DIM  90
#define HD      64
#define KP      70
#define E_TOT   (NG*EPG)

// ws layout (element offsets, 4B units)
#define WEFF_OFF   0                      // 4481 floats
#define EPACK_OFF  4608                   // 512*1440 u32
#define RS_OFF     (EPACK_OFF + NG*EPG)   // 512*96 int
#define D2_OFF     (RS_OFF + NG*96)       // 512*96 float
#define HW2_OFF    (D2_OFF + NG*96)       // 46080*64 float

// ---------------- K0: CSR build + weff fold ----------------
__global__ __launch_bounds__(256) void k0_csr(
    const int* __restrict__ ei, const float* __restrict__ ew,
    const float* __restrict__ lw1, const float* __restrict__ lb1,
    const float* __restrict__ lw2, const float* __restrict__ lb2,
    float* __restrict__ ws)
{
    __shared__ float s_deg[NPG];
    __shared__ int   s_indeg[NPG];
    __shared__ int   s_rowstart[NPG+1];
    __shared__ int   s_cursor[NPG];

    const int g = blockIdx.x, t = threadIdx.x;
    const int ebase = g*EPG, nbase = g*NPG;

    if (t < NPG) { s_deg[t] = 1.0f; s_indeg[t] = 0; }
    __syncthreads();
    for (int e = t; e < EPG; e += 256) {
        int d = ei[E_TOT + ebase + e] - nbase;
        atomicAdd(&s_deg[d], ew[ebase + e]);
        atomicAdd(&s_indeg[d], 1);
    }
    __syncthreads();
    if (t < NPG) s_deg[t] = rsqrtf(fmaxf(s_deg[t], 1e-12f));   // dinv in place
    if (t <= NPG) {
        int acc = 0;
        for (int i = 0; i < t; ++i) acc += s_indeg[i];
        s_rowstart[t] = acc;
        if (t < NPG) s_cursor[t] = acc;
    }
    __syncthreads();

    unsigned* epk = (unsigned*)ws + EPACK_OFF + g*EPG;
    for (int e = t; e < EPG; e += 256) {
        int s = ei[ebase + e] - nbase;
        int d = ei[E_TOT + ebase + e] - nbase;
        float nrm = s_deg[s] * ew[ebase + e] * s_deg[d];
        int pos = atomicAdd(&s_cursor[d], 1);
        epk[pos] = (__float_as_uint(nrm) & ~127u) | (unsigned)s;
    }
    if (t <= NPG) ((int*)ws)[RS_OFF + g*96 + t] = s_rowstart[t];
    if (t < NPG)  ws[D2_OFF + g*96 + t] = s_deg[t]*s_deg[t];

    // weff fold: blocks 0..17 cover i = 0..4607
    int i = g*256 + t;
    if (g < 18) {
        if (i < KP*HD) {
            const float4* row = (const float4*)(lw1 + (size_t)i*HD);
            const float4* w   = (const float4*)lw2;
            float s = 0.f;
            #pragma unroll
            for (int j4 = 0; j4 < HD/4; ++j4) {
                float4 r = row[j4], v = w[j4];
                s += r.x*v.x + r.y*v.y + r.z*v.z + r.w*v.w;
            }
            ws[WEFF_OFF + i] = s;
        } else if (i == KP*HD) {
            float s = lb2[0];
            for (int jj = 0; jj < HD; ++jj) s += lb1[jj]*lw2[jj];
            ws[WEFF_OFF + KP*HD] = s;
        }
    }
}

// ---------------- K1: xw = x @ W1 (16 rows / block) ----------------
__global__ __launch_bounds__(256) void k1_gemm1(
    const float* __restrict__ x, const float* __restrict__ W1,
    float* __restrict__ xw)     // xtrain region, transient
{
    __shared__ float sx[16*IN_DIM];
    const int t = threadIdx.x;
    const int row0 = blockIdx.x * 16;

    // stage 16 rows of x (1440 contiguous floats)
    const float4* gx = (const float4*)(x + (size_t)row0*IN_DIM);
    for (int i = t; i < 16*IN_DIM/4; i += 256) ((float4*)sx)[i] = gx[i];
    __syncthreads();

    const int j = t & 63, rg = t >> 6;     // 4 row-groups x 4 rows
    float a0 = 0.f, a1 = 0.f, a2 = 0.f, a3 = 0.f;
    const float2* xp0 = (const float2*)&sx[(rg*4+0)*IN_DIM];
    const float2* xp1 = (const float2*)&sx[(rg*4+1)*IN_DIM];
    const float2* xp2 = (const float2*)&sx[(rg*4+2)*IN_DIM];
    const float2* xp3 = (const float2*)&sx[(rg*4+3)*IN_DIM];
    #pragma unroll 9
    for (int kh = 0; kh < IN_DIM/2; ++kh) {
        float w0 = W1[(2*kh)*HD + j];
        float w1 = W1[(2*kh+1)*HD + j];
        float2 v0 = xp0[kh], v1 = xp1[kh], v2 = xp2[kh], v3 = xp3[kh];
        a0 += v0.x*w0 + v0.y*w1;
        a1 += v1.x*w0 + v1.y*w1;
        a2 += v2.x*w0 + v2.y*w1;
        a3 += v3.x*w0 + v3.y*w1;
    }
    float* o = xw + (size_t)(row0 + rg*4)*HD + j;
    o[0*HD] = a0; o[1*HD] = a1; o[2*HD] = a2; o[3*HD] = a3;
}

// ---------------- K2: scatter1 (graph x col-quarter), in-place ----------------
__global__ __launch_bounds__(256) void k2_scatter1(
    float* __restrict__ xt,      // holds xw; overwritten with h1 (pre-relu)
    const float* __restrict__ b1,
    const float* __restrict__ ws)
{
    __shared__ float    sxw[NPG*16];
    __shared__ unsigned sep[EPG];
    __shared__ int      srs[NPG+1];
    __shared__ float    sd2[NPG];

    const int t = threadIdx.x;
    const int g = blockIdx.x >> 2, q = blockIdx.x & 3;
    const int c0 = q*16, nbase = g*NPG;

    const unsigned* epk = (const unsigned*)ws + EPACK_OFF + g*EPG;
    for (int i = t; i < EPG; i += 256) sep[i] = epk[i];
    if (t <= NPG) srs[t] = ((const int*)ws)[RS_OFF + g*96 + t];
    if (t < NPG)  sd2[t] = ws[D2_OFF + g*96 + t];
    // stage xw[:, c0:c0+16]
    for (int i = t; i < NPG*4; i += 256) {
        int row = i >> 2, f = i & 3;
        ((float4*)sxw)[i] = *(const float4*)(xt + (size_t)(nbase+row)*HD + c0 + f*4);
    }
    __syncthreads();

    for (int o = t; o < NPG*16; o += 256) {
        int d = o >> 4, c = o & 15;
        float a = sd2[d]*sxw[o];
        int p0 = srs[d], p1 = srs[d+1];
        for (int p = p0; p < p1; ++p) {
            unsigned u = sep[p];
            a += __uint_as_float(u & ~127u) * sxw[(int)(u & 127u)*16 + c];
        }
        xt[(size_t)(nbase+d)*HD + c0 + c] = a + b1[c0+c];
    }
}

// ---------------- K3: hw2 = relu(h1) @ W2 ----------------
__global__ __launch_bounds__(256) void k3_gemm2(
    const float* __restrict__ xt, const float* __restrict__ W2,
    float* __restrict__ ws)
{
    __shared__ float sh[16*HD];
    const int t = threadIdx.x;
    const int row0 = blockIdx.x * 16;

    const float4* gh = (const float4*)(xt + (size_t)row0*HD);
    for (int i = t; i < 16*HD/4; i += 256) {
        float4 v = gh[i];
        v.x = fmaxf(v.x, 0.f); v.y = fmaxf(v.y, 0.f);
        v.z = fmaxf(v.z, 0.f); v.w = fmaxf(v.w, 0.f);
        ((float4*)sh)[i] = v;
    }
    __syncthreads();

    const int j = t & 63, rg = t >> 6;
    float a0 = 0.f, a1 = 0.f, a2 = 0.f, a3 = 0.f;
    #pragma unroll 4
    for (int k4 = 0; k4 < HD/4; ++k4) {
        int k = k4*4;
        float4 h0 = *(const float4*)&sh[(rg*4+0)*HD + k];
        float4 h1 = *(const float4*)&sh[(rg*4+1)*HD + k];
        float4 h2 = *(const float4*)&sh[(rg*4+2)*HD + k];
        float4 h3 = *(const float4*)&sh[(rg*4+3)*HD + k];
        float w0 = W2[(k+0)*HD + j];
        float w1 = W2[(k+1)*HD + j];
        float w2 = W2[(k+2)*HD + j];
        float w3 = W2[(k+3)*HD + j];
        a0 += h0.x*w0 + h0.y*w1 + h0.z*w2 + h0.w*w3;
        a1 += h1.x*w0 + h1.y*w1 + h1.z*w2 + h1.w*w3;
        a2 += h2.x*w0 + h2.y*w1 + h2.z*w2 + h2.w*w3;
        a3 += h3.x*w0 + h3.y*w1 + h3.z*w2 + h3.w*w3;
    }
    float* o = ws + HW2_OFF + (size_t)(row0 + rg*4)*HD + j;
    o[0*HD] = a0; o[1*HD] = a1; o[2*HD] = a2; o[3*HD] = a3;
}

// ---------------- K4: scatter2 + sort-pool + folded MLP ----------------
__global__ __launch_bounds__(512) void k4_final(
    const float* __restrict__ b2,
    const float* __restrict__ ws,
    float* __restrict__ out)
{
    __shared__ float    sB[NPG*HD];        // hw2
    __shared__ float    sC[NPG*HD];        // h2
    __shared__ unsigned sep[EPG];
    __shared__ int      srs[NPG+1];
    __shared__ float    sd2[NPG];
    __shared__ int      s_ranknode[KP];
    __shared__ float    s_red[8];

    const int g = blockIdx.x, t = threadIdx.x;
    const int j = t & 63, grp = t >> 6;
    const int nbase = g*NPG;

    const float4* gb = (const float4*)(ws + HW2_OFF + (size_t)nbase*HD);
    for (int i = t; i < NPG*HD/4; i += 512) ((float4*)sB)[i] = gb[i];
    const unsigned* epk = (const unsigned*)ws + EPACK_OFF + g*EPG;
    for (int i = t; i < EPG; i += 512) sep[i] = epk[i];
    if (t <= NPG) srs[t] = ((const int*)ws)[RS_OFF + g*96 + t];
    if (t < NPG)  sd2[t] = ws[D2_OFF + g*96 + t];
    __syncthreads();

    // scatter2
    for (int o = t; o < NPG*HD; o += 512) {
        int d = o >> 6, c = o & 63;
        float a = sd2[d]*sB[o];
        int p0 = srs[d], p1 = srs[d+1];
        for (int p = p0; p < p1; ++p) {
            unsigned u = sep[p];
            a += __uint_as_float(u & ~127u) * sB[(int)(u & 127u)*HD + c];
        }
        sC[o] = a + b2[c];
    }
    __syncthreads();

    // sort-pool rank (stable descending on channel 63)
    if (t < NPG) {
        float vi = sC[t*HD + (HD-1)];
        int rank = 0;
        for (int jj = 0; jj < NPG; ++jj) {
            float vj = sC[jj*HD + (HD-1)];
            rank += (vj > vi) || (vj == vi && jj < t);
        }
        if (rank < KP) s_ranknode[rank] = t;
    }
    __syncthreads();

    // folded MLP
    float part = 0.f;
    #pragma unroll
    for (int m = 0; m < 9; ++m) {
        int i = t + m*512;
        if (i < KP*HD) {
            int k = i >> 6, c = i & 63;
            part += ws[WEFF_OFF + i] * sC[s_ranknode[k]*HD + c];
        }
    }
    #pragma unroll
    for (int off = 32; off > 0; off >>= 1) part += __shfl_down(part, off, 64);
    if (j == 0) s_red[grp] = part;
    __syncthreads();
    if (t == 0) {
        float zz = ws[WEFF_OFF + KP*HD];
        #pragma unroll
        for (int m = 0; m < 8; ++m) zz += s_red[m];
        out[g] = 1.0f / (1.0f + expf(-zz));
    }
}

extern "C" void kernel_launch(void* const* d_in, const int* in_sizes, int n_in,
                              void* d_out, int out_size, void* d_ws, size_t ws_size,
                              hipStream_t stream) {
    const float* x   = (const float*)d_in[0];
    const int*   ei  = (const int*)  d_in[1];
    const float* ew  = (const float*)d_in[2];
    const float* W1  = (const float*)d_in[4];
    const float* b1  = (const float*)d_in[5];
    const float* W2  = (const float*)d_in[6];
    const float* b2  = (const float*)d_in[7];
    const float* lw1 = (const float*)d_in[8];
    const float* lb1 = (const float*)d_in[9];
    const float* lw2 = (const float*)d_in[10];
    const float* lb2 = (const float*)d_in[11];

    float* ws     = (float*)d_ws;
    float* out    = (float*)d_out;        // [512]
    float* xtrain = out + NG;             // [46080*64]

    k0_csr    <<<NG,   256, 0, stream>>>(ei, ew, lw1, lb1, lw2, lb2, ws);
    k1_gemm1  <<<2880, 256, 0, stream>>>(x, W1, xtrain);
    k2_scatter1<<<NG*4, 256, 0, stream>>>(xtrain, b1, ws);
    k3_gemm2  <<<2880, 256, 0, stream>>>(xtrain, W2, ws);
    k4_final  <<<NG,   512, 0, stream>>>(b2, ws, out);
}